// Round 1
// baseline (45578.711 us; speedup 1.0000x reference)
//
#include <hip/hip_runtime.h>
#include <stdint.h>
#include <stddef.h>

// Problem constants (ESN_58317065945127)
#define B_    128
#define T_    2048
#define D_    128
#define H_    1024
#define O_    32
#define LAST_ 20

// Partition: 8 batch-blocks x 16 col-blocks = 128 WGs of 256 threads.
// Each wave owns a [16 batch x 16 col] tile; master h stays in registers (fp32).
#define NB_   8
#define NC_   16
#define RING_ 4      // h exchange ring depth (>=2 is provably safe with the t-1 poll)
#define FPAD_ 16     // ints per flag slot (64B padding, avoids false sharing)

typedef __bf16 bf16x8 __attribute__((ext_vector_type(8)));
typedef float  f32x4  __attribute__((ext_vector_type(4)));

__device__ __forceinline__ float tanh_fast(float s) {
    // tanh(x) = (e^{2x}-1)/(e^{2x}+1); clamp avoids overflow, tanh saturated anyway
    float a = fminf(fmaxf(s, -12.0f), 12.0f);
    float e = __expf(2.0f * a);
    return (e - 1.0f) / (e + 1.0f);
}

// Persistent kernel: runs the whole T=2048 recurrence.
// Fragment layouts (gfx950 mfma_f32_16x16x32_bf16, HW-verified per guide):
//   A: lane holds A[m=lane&15][k=(lane>>4)*8 + j]      (h rows = batches)
//   B: lane holds B[k=(lane>>4)*8 + j][n=lane&15]      (w_r cols)
//   C/D: col = lane&15, row = (lane>>4)*4 + reg
__global__ __launch_bounds__(256, 1) void esn_persist(
    const float* __restrict__ x, const float* __restrict__ w_in,
    const float* __restrict__ w_r, __bf16* __restrict__ h_ex,
    float* __restrict__ hs, int* __restrict__ flags)
{
    const int wg  = (int)blockIdx.x;
    const int bb  = wg & (NB_ - 1);  // &7: cohort likely lands on one XCD (%8 round-robin)
    const int cb  = wg >> 3;
    const int tid = (int)threadIdx.x;
    const int wv  = tid >> 6;
    const int ln  = tid & 63;
    const int m   = ln & 15;   // A-row (batch) for A-frags; B/D col for B,C/D frags
    const int q   = ln >> 4;   // quad
    const int b0  = bb * 16;
    const int n0  = cb * 64 + wv * 16;

    // ---- one-time: weight fragments into registers (B-operand layout) ----
    bf16x8 win[4];                       // w_in[:, n0+m], K=128 -> 4 chunks
    #pragma unroll
    for (int c = 0; c < 4; ++c) {
        bf16x8 f;
        #pragma unroll
        for (int j = 0; j < 8; ++j)
            f[j] = (__bf16)w_in[(size_t)(c * 32 + q * 8 + j) * H_ + (n0 + m)];
        win[c] = f;
    }
    bf16x8 wr[32];                       // w_r[:, n0+m], K=1024 -> 32 chunks (128 VGPR)
    #pragma unroll
    for (int kc = 0; kc < 32; ++kc) {
        bf16x8 f;
        #pragma unroll
        for (int j = 0; j < 8; ++j)
            f[j] = (__bf16)w_r[(size_t)(kc * 32 + q * 8 + j) * H_ + (n0 + m)];
        wr[kc] = f;
    }

    // Spin deadline: ~3s at 100 MHz realtime clock. Only fires on a sync bug;
    // guarantees the kernel returns instead of hanging graph replay.
    const unsigned long long tdead =
        __builtin_amdgcn_s_memrealtime() + 300000000ull;

    int* myflag = &flags[(bb * NC_ + cb) * FPAD_];
    const float* xrow = x + (size_t)(b0 + m) * T_ * D_ + q * 8;

    float hm0 = 0.f, hm1 = 0.f, hm2 = 0.f, hm3 = 0.f;  // fp32 master h (C-layout)

    for (int t = 0; t < T_; ++t) {
        // x A-fragments for the input projection (independent of sync -> issue early)
        f32x4 xlo[4], xhi[4];
        const float* xp = xrow + (size_t)t * D_;
        #pragma unroll
        for (int c = 0; c < 4; ++c) {
            xlo[c] = *(const f32x4*)(xp + c * 32);
            xhi[c] = *(const f32x4*)(xp + c * 32 + 4);
        }

        if (t > 0) {
            // wait for cohort (same batch-block) to publish h_{t-1}
            if (tid < NC_) {
                const int want = t - 1;
                while (__hip_atomic_load(&flags[(bb * NC_ + tid) * FPAD_],
                                         __ATOMIC_RELAXED,
                                         __HIP_MEMORY_SCOPE_AGENT) < want) {
                    if (__builtin_amdgcn_s_memrealtime() > tdead) break;
                }
            }
            __syncthreads();
            __threadfence();  // acquire: invalidate L1/L2 so h reads see LLC data
        }

        f32x4 acc = {0.f, 0.f, 0.f, 0.f};

        // issue all 32 h A-loads first (latency overlapped by xw MFMAs below)
        bf16x8 af[32];
        const __bf16* hp = h_ex
            + (size_t)((t + RING_ - 1) & (RING_ - 1)) * (B_ * H_)
            + (size_t)(b0 + m) * H_ + q * 8;
        if (t > 0) {
            #pragma unroll
            for (int kc = 0; kc < 32; ++kc)
                af[kc] = *(const bf16x8*)(hp + kc * 32);
        }

        // input projection: acc = x_t @ w_in (4 MFMAs over D=128)
        #pragma unroll
        for (int c = 0; c < 4; ++c) {
            bf16x8 a;
            #pragma unroll
            for (int j = 0; j < 4; ++j) {
                a[j]     = (__bf16)xlo[c][j];
                a[j + 4] = (__bf16)xhi[c][j];
            }
            acc = __builtin_amdgcn_mfma_f32_16x16x32_bf16(a, win[c], acc, 0, 0, 0);
        }

        // recurrent part: acc += h_{t-1} @ w_r (32 MFMAs over K=1024)
        if (t > 0) {
            #pragma unroll
            for (int kc = 0; kc < 32; ++kc)
                acc = __builtin_amdgcn_mfma_f32_16x16x32_bf16(af[kc], wr[kc], acc, 0, 0, 0);
        }

        const float th0 = tanh_fast(acc[0]);
        const float th1 = tanh_fast(acc[1]);
        const float th2 = tanh_fast(acc[2]);
        const float th3 = tanh_fast(acc[3]);
        if (t == 0) {           // reference: h = tanh(xw[:,0]), no leak at t=0
            hm0 = th0; hm1 = th1; hm2 = th2; hm3 = th3;
        } else {                // h = (1-0.9)h + 0.9*tanh(.)
            hm0 = 0.1f * hm0 + 0.9f * th0;
            hm1 = 0.1f * hm1 + 0.9f * th1;
            hm2 = 0.1f * hm2 + 0.9f * th2;
            hm3 = 0.1f * hm3 + 0.9f * th3;
        }

        // publish bf16 slice (C/D layout -> [b][c] memory)
        __bf16* op = h_ex + (size_t)(t & (RING_ - 1)) * (B_ * H_)
                   + (size_t)(b0 + q * 4) * H_ + (n0 + m);
        op[0 * H_] = (__bf16)hm0;
        op[1 * H_] = (__bf16)hm1;
        op[2 * H_] = (__bf16)hm2;
        op[3 * H_] = (__bf16)hm3;

        // tail collection for the readout (fp32 master values)
        if (t >= T_ - LAST_) {
            float* sp = hs + (size_t)(t - (T_ - LAST_)) * (B_ * H_)
                      + (size_t)(b0 + q * 4) * H_ + (n0 + m);
            sp[0 * H_] = hm0;
            sp[1 * H_] = hm1;
            sp[2 * H_] = hm2;
            sp[3 * H_] = hm3;
        }

        __threadfence();  // release: drain stores + writeback L2 to LLC
        __syncthreads();
        if (tid == 0)
            __hip_atomic_store(myflag, t, __ATOMIC_RELEASE,
                               __HIP_MEMORY_SCOPE_AGENT);
    }
}

// Readout: out[b,:] = cat(hs)[b,:] @ W + bias.  One block per batch row.
__global__ __launch_bounds__(256) void esn_out(
    const float* __restrict__ hs, const float* __restrict__ Wm,
    const float* __restrict__ bias, float* __restrict__ out)
{
    const int b   = (int)blockIdx.x;
    const int tid = (int)threadIdx.x;
    float acc[O_];
    #pragma unroll
    for (int o = 0; o < O_; ++o) acc[o] = 0.f;

    for (int k = tid; k < LAST_ * H_; k += 256) {
        // cat order: k = t'*H + c  <->  hs[t'][b][c]
        const float hv = hs[(size_t)(k >> 10) * (B_ * H_) + (size_t)b * H_ + (k & (H_ - 1))];
        const f32x4* wp = (const f32x4*)(Wm + (size_t)k * O_);
        #pragma unroll
        for (int v = 0; v < 8; ++v) {
            f32x4 w4 = wp[v];
            acc[4 * v + 0] = fmaf(hv, w4[0], acc[4 * v + 0]);
            acc[4 * v + 1] = fmaf(hv, w4[1], acc[4 * v + 1]);
            acc[4 * v + 2] = fmaf(hv, w4[2], acc[4 * v + 2]);
            acc[4 * v + 3] = fmaf(hv, w4[3], acc[4 * v + 3]);
        }
    }

    __shared__ float red[256][O_ + 1];  // +1 pad: conflict-free column sums
    #pragma unroll
    for (int o = 0; o < O_; ++o) red[tid][o] = acc[o];
    __syncthreads();
    if (tid < O_) {
        float s = bias[tid];
        for (int i = 0; i < 256; ++i) s += red[i][tid];
        out[(size_t)b * O_ + tid] = s;
    }
}

extern "C" void kernel_launch(void* const* d_in, const int* in_sizes, int n_in,
                              void* d_out, int out_size, void* d_ws, size_t ws_size,
                              hipStream_t stream)
{
    const float* x    = (const float*)d_in[0];  // [128,2048,128]
    const float* w_in = (const float*)d_in[1];  // [128,1024]
    const float* w_r  = (const float*)d_in[2];  // [1024,1024]
    const float* Wm   = (const float*)d_in[3];  // [20480,32]
    const float* bias = (const float*)d_in[4];  // [32]
    float* out        = (float*)d_out;          // [128,32]

    const size_t flag_bytes = (size_t)NB_ * NC_ * FPAD_ * sizeof(int);   // 8 KiB
    const size_t hex_bytes  = (size_t)RING_ * B_ * H_ * sizeof(__bf16);  // 1 MiB
    const size_t hs_bytes   = (size_t)LAST_ * B_ * H_ * sizeof(float);   // 10 MiB
    if (ws_size < flag_bytes + hex_bytes + hs_bytes) return;  // fail loud, not corrupt

    int*    flags = (int*)d_ws;
    __bf16* h_ex  = (__bf16*)((char*)d_ws + flag_bytes);
    float*  hs    = (float*)((char*)d_ws + flag_bytes + hex_bytes);

    // flags = -1 ("nothing published"); ws is re-poisoned 0xAA before every call
    hipMemsetAsync(flags, 0xFF, flag_bytes, stream);

    hipLaunchKernelGGL(esn_persist, dim3(NB_ * NC_), dim3(256), 0, stream,
                       x, w_in, w_r, h_ex, hs, flags);
    hipLaunchKernelGGL(esn_out, dim3(B_), dim3(256), 0, stream,
                       hs, Wm, bias, out);
}

// Round 2
// 19401.711 us; speedup vs baseline: 2.3492x; 2.3492x over previous
//
#include <hip/hip_runtime.h>
#include <stdint.h>
#include <stddef.h>

// Problem constants (ESN_58317065945127)
#define B_    128
#define T_    2048
#define D_    128
#define H_    1024
#define O_    32
#define LAST_ 20

// Partition: 8 batch-blocks x 16 col-blocks = 128 WGs of 256 threads.
// Each wave owns a [16 batch x 16 col] tile of h; master h stays in fp32 regs.
#define NB_   8
#define NC_   16
#define RING_ 4      // h exchange ring depth (>=2 provably safe with the t-1 poll)
#define FPAD_ 16     // ints per flag slot (64B padding, avoids false sharing)

typedef __bf16 bf16x8 __attribute__((ext_vector_type(8)));
typedef __bf16 bf16x4 __attribute__((ext_vector_type(4)));
typedef float  f32x4  __attribute__((ext_vector_type(4)));

union Pack8  { unsigned long long u;    bf16x4 v; };
union Pack16 { unsigned long long u[2]; bf16x8 v; };

__device__ __forceinline__ float tanh_fast(float s) {
    float a = fminf(fmaxf(s, -12.0f), 12.0f);
    float e = __expf(2.0f * a);
    return (e - 1.0f) / (e + 1.0f);
}

// All cross-WG data moves via relaxed AGENT-scope atomics -> plain sc1
// loads/stores straight to LLC. NO __threadfence anywhere: agent fences on
// gfx950 emit buffer_wbl2/buffer_inv (L2-wide flush/invalidate) which was the
// 22 us/step stall in R1. Release = s_waitcnt vmcnt(0) (LLC store-ack) before
// the relaxed flag store; acquire is free since h reads are sc1 (LLC-direct).
//
// Transposed compute: h_new^T = w_r^T @ h^T.
//   A-frag (weights, reg-resident): A[m=ln&15 -> col c][k=q*8+j] = w_r[k][c]
//   B-frag (h / x):                 B[k=q*8+j][n=ln&15 -> batch b] = h[b][k]
//   C/D: col(ln&15)=batch, row(q*4+reg)=c  -> lane owns 4 CONSECUTIVE c at
//        fixed b: publish = one packed 8B store, hs = one 16B store.
__global__ __launch_bounds__(256, 1) void esn_persist(
    const float* __restrict__ x, const float* __restrict__ w_in,
    const float* __restrict__ w_r, __bf16* __restrict__ h_ex,
    float* __restrict__ hs, int* __restrict__ flags)
{
    const int wg  = (int)blockIdx.x;
    const int bb  = wg & (NB_ - 1);  // &7: cohort likely co-lands on one XCD (perf only)
    const int cb  = wg >> 3;
    const int tid = (int)threadIdx.x;
    const int wv  = tid >> 6;
    const int ln  = tid & 63;
    const int nn  = ln & 15;   // batch index within tile (B-operand n / D col)
    const int q   = ln >> 4;   // quad
    const int b0  = bb * 16;
    const int n0  = cb * 64 + wv * 16;

    // ---- one-time: weight fragments into registers (A-operand layout) ----
    // A[m][k] = w^T[c][k] = w[k][c] with c = n0+nn ... same elements as the
    // old B-frags, so the gather code is unchanged.
    bf16x8 win[4];                       // w_in, K=128 -> 4 chunks
    #pragma unroll
    for (int c = 0; c < 4; ++c) {
        bf16x8 f;
        #pragma unroll
        for (int j = 0; j < 8; ++j)
            f[j] = (__bf16)w_in[(size_t)(c * 32 + q * 8 + j) * H_ + (n0 + nn)];
        win[c] = f;
    }
    bf16x8 wr[32];                       // w_r, K=1024 -> 32 chunks (128 VGPR)
    #pragma unroll
    for (int kc = 0; kc < 32; ++kc) {
        bf16x8 f;
        #pragma unroll
        for (int j = 0; j < 8; ++j)
            f[j] = (__bf16)w_r[(size_t)(kc * 32 + q * 8 + j) * H_ + (n0 + nn)];
        wr[kc] = f;
    }

    // Spin deadline ~3s: only fires on a sync bug; guarantees return.
    const unsigned long long tdead =
        __builtin_amdgcn_s_memrealtime() + 300000000ull;

    int* myflag = &flags[(bb * NC_ + cb) * FPAD_];
    const float* xrow = x + (size_t)(b0 + nn) * T_ * D_ + q * 8;  // x[b][t][k]
    const size_t hrow = (size_t)(b0 + nn) * H_;                   // h_ex row base

    float hm0 = 0.f, hm1 = 0.f, hm2 = 0.f, hm3 = 0.f;  // fp32 master h (D layout)

    for (int t = 0; t < T_; ++t) {
        // x B-fragments (plain cached loads; caches stay warm — no inv now)
        f32x4 xlo[4], xhi[4];
        const float* xp = xrow + (size_t)t * D_;
        #pragma unroll
        for (int c = 0; c < 4; ++c) {
            xlo[c] = *(const f32x4*)(xp + c * 32);
            xhi[c] = *(const f32x4*)(xp + c * 32 + 4);
        }

        if (t > 0) {
            // wait for cohort (same batch-block) to publish h_{t-1}
            if (tid < NC_) {
                const int want = t - 1;
                while (__hip_atomic_load(&flags[(bb * NC_ + tid) * FPAD_],
                                         __ATOMIC_RELAXED,
                                         __HIP_MEMORY_SCOPE_AGENT) < want) {
                    if (__builtin_amdgcn_s_memrealtime() > tdead) break;
                }
            }
            __syncthreads();
        }

        f32x4 acc = {0.f, 0.f, 0.f, 0.f};

        // h B-fragments: sc1 loads (LLC-coherent), issue all before MFMAs
        bf16x8 af[32];
        if (t > 0) {
            const __bf16* hp = h_ex
                + (size_t)((t + RING_ - 1) & (RING_ - 1)) * (B_ * H_)
                + hrow + q * 8;
            #pragma unroll
            for (int kc = 0; kc < 32; ++kc) {
                Pack16 pk;
                pk.u[0] = __hip_atomic_load(
                    (const unsigned long long*)(hp + kc * 32),
                    __ATOMIC_RELAXED, __HIP_MEMORY_SCOPE_AGENT);
                pk.u[1] = __hip_atomic_load(
                    (const unsigned long long*)(hp + kc * 32 + 4),
                    __ATOMIC_RELAXED, __HIP_MEMORY_SCOPE_AGENT);
                af[kc] = pk.v;
            }
        }

        // input projection: acc += (w_in^T @ x_t^T) tile (4 MFMAs over D=128)
        #pragma unroll
        for (int c = 0; c < 4; ++c) {
            bf16x8 bfr;
            #pragma unroll
            for (int j = 0; j < 4; ++j) {
                bfr[j]     = (__bf16)xlo[c][j];
                bfr[j + 4] = (__bf16)xhi[c][j];
            }
            acc = __builtin_amdgcn_mfma_f32_16x16x32_bf16(win[c], bfr, acc, 0, 0, 0);
        }

        // recurrent part: acc += (w_r^T @ h^T) tile (32 MFMAs over K=1024)
        if (t > 0) {
            #pragma unroll
            for (int kc = 0; kc < 32; ++kc)
                acc = __builtin_amdgcn_mfma_f32_16x16x32_bf16(wr[kc], af[kc], acc, 0, 0, 0);
        }

        const float th0 = tanh_fast(acc[0]);
        const float th1 = tanh_fast(acc[1]);
        const float th2 = tanh_fast(acc[2]);
        const float th3 = tanh_fast(acc[3]);
        if (t == 0) {           // reference: h = tanh(xw[:,0]), no leak at t=0
            hm0 = th0; hm1 = th1; hm2 = th2; hm3 = th3;
        } else {                // h = 0.1*h + 0.9*tanh(.)
            hm0 = 0.1f * hm0 + 0.9f * th0;
            hm1 = 0.1f * hm1 + 0.9f * th1;
            hm2 = 0.1f * hm2 + 0.9f * th2;
            hm3 = 0.1f * hm3 + 0.9f * th3;
        }

        // publish: lane owns h[b0+nn][n0+q*4 .. +3] -> one packed 8B sc1 store
        {
            Pack8 p;
            p.v = (bf16x4){(__bf16)hm0, (__bf16)hm1, (__bf16)hm2, (__bf16)hm3};
            unsigned long long* op = (unsigned long long*)
                (h_ex + (size_t)(t & (RING_ - 1)) * (B_ * H_)
                      + hrow + n0 + q * 4);
            __hip_atomic_store(op, p.u, __ATOMIC_RELAXED,
                               __HIP_MEMORY_SCOPE_AGENT);
        }

        // tail collection for the readout (fp32, one 16B store)
        if (t >= T_ - LAST_) {
            f32x4* sp = (f32x4*)(hs + (size_t)(t - (T_ - LAST_)) * (B_ * H_)
                                    + hrow + n0 + q * 4);
            *sp = (f32x4){hm0, hm1, hm2, hm3};
        }

        // release: LLC store-ack for this wave's publish, then WG barrier
        // (compiler also drains vmcnt at s_barrier), then flag. NO wbl2.
        asm volatile("s_waitcnt vmcnt(0)" ::: "memory");
        __syncthreads();
        if (tid == 0)
            __hip_atomic_store(myflag, t, __ATOMIC_RELAXED,
                               __HIP_MEMORY_SCOPE_AGENT);
    }
}

// Readout: out[b,:] = cat(hs)[b,:] @ W + bias.  One block per batch row.
__global__ __launch_bounds__(256) void esn_out(
    const float* __restrict__ hs, const float* __restrict__ Wm,
    const float* __restrict__ bias, float* __restrict__ out)
{
    const int b   = (int)blockIdx.x;
    const int tid = (int)threadIdx.x;
    float acc[O_];
    #pragma unroll
    for (int o = 0; o < O_; ++o) acc[o] = 0.f;

    for (int k = tid; k < LAST_ * H_; k += 256) {
        // cat order: k = t'*H + c  <->  hs[t'][b][c]
        const float hv = hs[(size_t)(k >> 10) * (B_ * H_) + (size_t)b * H_ + (k & (H_ - 1))];
        const f32x4* wp = (const f32x4*)(Wm + (size_t)k * O_);
        #pragma unroll
        for (int v = 0; v < 8; ++v) {
            f32x4 w4 = wp[v];
            acc[4 * v + 0] = fmaf(hv, w4[0], acc[4 * v + 0]);
            acc[4 * v + 1] = fmaf(hv, w4[1], acc[4 * v + 1]);
            acc[4 * v + 2] = fmaf(hv, w4[2], acc[4 * v + 2]);
            acc[4 * v + 3] = fmaf(hv, w4[3], acc[4 * v + 3]);
        }
    }

    __shared__ float red[256][O_ + 1];  // +1 pad: conflict-free column sums
    #pragma unroll
    for (int o = 0; o < O_; ++o) red[tid][o] = acc[o];
    __syncthreads();
    if (tid < O_) {
        float s = bias[tid];
        for (int i = 0; i < 256; ++i) s += red[i][tid];
        out[(size_t)b * O_ + tid] = s;
    }
}

extern "C" void kernel_launch(void* const* d_in, const int* in_sizes, int n_in,
                              void* d_out, int out_size, void* d_ws, size_t ws_size,
                              hipStream_t stream)
{
    const float* x    = (const float*)d_in[0];  // [128,2048,128]
    const float* w_in = (const float*)d_in[1];  // [128,1024]
    const float* w_r  = (const float*)d_in[2];  // [1024,1024]
    const float* Wm   = (const float*)d_in[3];  // [20480,32]
    const float* bias = (const float*)d_in[4];  // [32]
    float* out        = (float*)d_out;          // [128,32]

    const size_t flag_bytes = (size_t)NB_ * NC_ * FPAD_ * sizeof(int);   // 8 KiB
    const size_t hex_bytes  = (size_t)RING_ * B_ * H_ * sizeof(__bf16);  // 1 MiB
    const size_t hs_bytes   = (size_t)LAST_ * B_ * H_ * sizeof(float);   // 10 MiB
    if (ws_size < flag_bytes + hex_bytes + hs_bytes) return;  // fail loud, not corrupt

    int*    flags = (int*)d_ws;
    __bf16* h_ex  = (__bf16*)((char*)d_ws + flag_bytes);
    float*  hs    = (float*)((char*)d_ws + flag_bytes + hex_bytes);

    // flags = -1 ("nothing published"); ws is re-poisoned 0xAA before every call
    hipMemsetAsync(flags, 0xFF, flag_bytes, stream);

    hipLaunchKernelGGL(esn_persist, dim3(NB_ * NC_), dim3(256), 0, stream,
                       x, w_in, w_r, h_ex, hs, flags);
    hipLaunchKernelGGL(esn_out, dim3(B_), dim3(256), 0, stream,
                       hs, Wm, bias, out);
}